// Round 1
// baseline (126.235 us; speedup 1.0000x reference)
//
#include <hip/hip_runtime.h>
#include <math.h>

#define NUM_CLASSES 80
#define C_CH (NUM_CLASSES + 1)
#define MAX_T 128              // per-(image,scale) target capacity (T=64 here)
#define NG 4                   // channel-groups per (image,scale) for focal gather
#define CPG (NUM_CLASSES / NG) // 20 channels per group

__device__ __forceinline__ float softplusf(float x) {
    return fmaxf(x, 0.f) + log1pf(expf(-fabsf(x)));
}
__device__ __forceinline__ float sigmoidf_(float x) {
    return 1.f / (1.f + expf(-x));
}

// ---------------------------------------------------------------------------
// Grid layout (all blocks 256 threads):
//   [0, nbg4)             bg: p4 channel-0 plane sums, 4 blocks/image, float4
//   [nbg4, nbg)           bg: p5 channel-0 plane sums, 1 block/image, float4
//   [nbg, nbg+nA1)        focal: one (image,scale,channel-group) per block,
//                         channel-major gather (64 lanes = 64 targets in ONE plane)
//   [nbg+nA1, +nA2)       per-(image,scale): obj + bbox + dedup/occupancy
// ws: bgpart[nbg] | lcpart[nA1] | a2part[2B*5]  — all written every call
// ---------------------------------------------------------------------------
__global__ void __launch_bounds__(256) fused_kernel(
    const float* __restrict__ cls_p4, const float* __restrict__ reg_p4,
    const float* __restrict__ cls_p5, const float* __restrict__ reg_p5,
    const int* __restrict__ t4_cls, const float* __restrict__ t4_box, const float* __restrict__ t4_mask,
    const int* __restrict__ t5_cls, const float* __restrict__ t5_box, const float* __restrict__ t5_mask,
    float* __restrict__ bgpart, float* __restrict__ lcpart, float* __restrict__ a2part,
    int B, int T, int nbg4, int nbg5, int nA1)
{
    const int tid  = threadIdx.x;
    const int wave = tid >> 6;
    const int lane = tid & 63;
    const int nbg  = nbg4 + nbg5;
    const int bx   = (int)blockIdx.x;

    if (bx < nbg) {
        // ---------- role B: background plane sum of softplus(channel 0) ----------
        const float4* src;
        if (bx < nbg4) {
            int b = bx >> 2, j = bx & 3;            // 4 blocks/image, 1600 cells each
            src = (const float4*)(cls_p4 + (size_t)b * (C_CH * 6400) + j * 1600);
        } else {
            int b = bx - nbg4;                      // 1 block/image, 1600 cells
            src = (const float4*)(cls_p5 + (size_t)b * (C_CH * 1600));
        }
        float sp = 0.f;
        {
            float4 v = src[tid];
            sp += softplusf(v.x) + softplusf(v.y) + softplusf(v.z) + softplusf(v.w);
            if (tid < 144) {                        // 400 float4s total
                float4 w2 = src[tid + 256];
                sp += softplusf(w2.x) + softplusf(w2.y) + softplusf(w2.z) + softplusf(w2.w);
            }
        }
        for (int off = 32; off > 0; off >>= 1) sp += __shfl_down(sp, off, 64);
        __shared__ float sbg[4];
        if (lane == 0) sbg[wave] = sp;
        __syncthreads();
        if (tid == 0) bgpart[bx] = sbg[0] + sbg[1] + sbg[2] + sbg[3];
        return;
    }

    if (bx < nbg + nA1) {
        // ---------- role A1: focal class loss, channel-major gather ----------
        const int q = bx - nbg;
        const int p = q >> 2;                       // (image,scale) pair, NG==4
        const int g = q & 3;                        // channel group
        const int scale = (p >= B) ? 1 : 0;
        const int b = scale ? (p - B) : p;

        const float* cls_p; const int* tc; const float* tb_; const float* tm;
        int W;
        if (!scale) { cls_p = cls_p4; tc = t4_cls; tb_ = t4_box; tm = t4_mask; W = 80; }
        else        { cls_p = cls_p5; tc = t5_cls; tb_ = t5_box; tm = t5_mask; W = 40; }
        const int HW = W * W;                       // H == W for both scales
        const float* img = cls_p + (size_t)b * C_CH * HW;

        __shared__ int   s1_cell[64];
        __shared__ float s1_mask[64];
        __shared__ int   s1_cid[64];
        __shared__ float s1_red[4];

        float lc_acc = 0.f;
        for (int t0 = 0; t0 < T; t0 += 64) {
            if (tid < 64) {
                int tt = t0 + tid;
                int cell = 0; float m = 0.f; int cid = -1;
                if (tt < T) {
                    int ti = b * T + tt;
                    m   = tm[ti];
                    cid = tc[ti];
                    float tx = tb_[ti * 4 + 0] * (float)W;
                    float ty = tb_[ti * 4 + 1] * (float)W;
                    int gx = (int)fminf(fmaxf(tx, 0.f), (float)(W - 1));
                    int gy = (int)fminf(fmaxf(ty, 0.f), (float)(W - 1));
                    cell = gy * W + gx;
                }
                s1_cell[tid] = cell; s1_mask[tid] = m; s1_cid[tid] = cid;
            }
            __syncthreads();
            const int   cell = s1_cell[lane];
            const float m    = s1_mask[lane];
            const int   cid  = s1_cid[lane];
            const float* basep = img + cell;
            float fs = 0.f;
            #pragma unroll
            for (int k = 0; k < CPG / 4; k++) {     // 5 independent loads in flight
                int c = g * CPG + wave + k * 4;     // class channel 0..79
                float x = basep[(size_t)(c + 1) * HW];
                float tgt = (c == cid) ? 1.f : 0.f;
                float bce = softplusf(x) - x * tgt;
                float pq  = sigmoidf_(x);
                float pt  = pq * tgt + (1.f - pq) * (1.f - tgt);
                float om  = 1.f - pt;
                fs += 0.25f * om * om * bce;
            }
            lc_acc += fs * m;
            __syncthreads();
        }
        for (int off = 32; off > 0; off >>= 1) lc_acc += __shfl_down(lc_acc, off, 64);
        if (lane == 0) s1_red[wave] = lc_acc;
        __syncthreads();
        if (tid == 0)
            lcpart[q] = (s1_red[0] + s1_red[1] + s1_red[2] + s1_red[3]) * (1.f / (float)NUM_CLASSES);
        return;
    }

    // ---------- role A2: per-(image,scale) obj + bbox + dedup/occupancy ----------
    {
        const int p = bx - nbg - nA1;
        const int scale = (p >= B) ? 1 : 0;
        const int b = scale ? (p - B) : p;
        const float* cls_p; const float* reg_p; const float* tb_; const float* tm;
        int W;
        if (!scale) { cls_p = cls_p4; reg_p = reg_p4; tb_ = t4_box; tm = t4_mask; W = 80; }
        else        { cls_p = cls_p5; reg_p = reg_p5; tb_ = t5_box; tm = t5_mask; W = 40; }
        const int HW = W * W;
        const int TT = (T < MAX_T) ? T : MAX_T;

        __shared__ int   s_cell[MAX_T];
        __shared__ float s_mask[MAX_T];
        __shared__ float s_sp0[MAX_T];
        __shared__ float s_tx[MAX_T], s_ty[MAX_T], s_tw[MAX_T], s_th[MAX_T];
        __shared__ float s_reg[4][64];
        __shared__ float s_red[4][5];

        for (int i = tid; i < TT; i += 256) {
            int ti = b * T + i;
            float m  = tm[ti];
            float tx = tb_[ti * 4 + 0] * (float)W;
            float ty = tb_[ti * 4 + 1] * (float)W;
            float tw = tb_[ti * 4 + 2] * (float)W;
            float th = tb_[ti * 4 + 3] * (float)W;
            int gx = (int)fminf(fmaxf(tx, 0.f), (float)(W - 1));
            int gy = (int)fminf(fmaxf(ty, 0.f), (float)(W - 1));
            s_cell[i] = gy * W + gx;
            s_mask[i] = m;
            s_tx[i] = tx; s_ty[i] = ty; s_tw[i] = tw; s_th[i] = th;
        }
        __syncthreads();

        float lb = 0.f, lo = 0.f, n = 0.f, osp = 0.f, ocnt = 0.f;

        for (int t0 = 0; t0 < TT; t0 += 64) {
            const int t = t0 + lane;
            const bool tv = (t < TT);
            const int cell  = tv ? s_cell[t] : 0;
            const float m   = tv ? s_mask[t] : 0.f;

            // channel-major reg gather: wave w loads reg channel w for all targets
            s_reg[wave][lane] = reg_p[((size_t)b * 4 + wave) * HW + cell];
            if (wave == 0) {
                float x0 = cls_p[(size_t)b * C_CH * HW + cell];
                lo += softplusf(-x0) * m;
                n  += m;
                if (tv) s_sp0[t] = softplusf(x0);
            }
            __syncthreads();
            if (wave == 0 && tv) {
                float rv0 = s_reg[0][lane], rv1 = s_reg[1][lane];
                float rv2 = s_reg[2][lane], rv3 = s_reg[3][lane];
                float tx = s_tx[t], ty = s_ty[t], tw = s_tw[t], th = s_th[t];
                int gx = (int)fminf(fmaxf(tx, 0.f), (float)(W - 1));
                int gy = (int)fminf(fmaxf(ty, 0.f), (float)(W - 1));
                float dx = sigmoidf_(rv0), dy = sigmoidf_(rv1);
                float dw = expf(fminf(fmaxf(rv2, -4.f), 4.f));
                float dh = expf(fminf(fmaxf(rv3, -4.f), 4.f));
                float px = (float)gx + dx, py = (float)gy + dy;
                float pb0 = px - dw * 0.5f, pb1 = py - dh * 0.5f;
                float pb2 = px + dw * 0.5f, pb3 = py + dh * 0.5f;
                float tb0 = tx - tw * 0.5f, tb1 = ty - th * 0.5f;
                float tb2 = tx + tw * 0.5f, tb3 = ty + th * 0.5f;
                float s = 0.f, d, a;
                d = pb0 - tb0; a = fabsf(d); s += (a < 1.f) ? 0.5f * d * d : a - 0.5f;
                d = pb1 - tb1; a = fabsf(d); s += (a < 1.f) ? 0.5f * d * d : a - 0.5f;
                d = pb2 - tb2; a = fabsf(d); s += (a < 1.f) ? 0.5f * d * d : a - 0.5f;
                d = pb3 - tb3; a = fabsf(d); s += (a < 1.f) ? 0.5f * d * d : a - 0.5f;
                lb += (s * 0.25f) * m;
            }
            __syncthreads();
        }

        // dedup: unique occupied cells among masked targets (first-occurrence wins)
        for (int i = tid; i < TT; i += 256) {
            if (s_mask[i] > 0.f) {
                int ci = s_cell[i];
                bool first = true;
                for (int j = 0; j < i; j++)
                    if (s_mask[j] > 0.f && s_cell[j] == ci) { first = false; break; }
                if (first) { osp += s_sp0[i]; ocnt += 1.f; }
            }
        }

        float vals[5] = { lb, lo, n, osp, ocnt };
        #pragma unroll
        for (int k = 0; k < 5; k++) {
            float v = vals[k];
            for (int off = 32; off > 0; off >>= 1) v += __shfl_down(v, off, 64);
            vals[k] = v;
        }
        if (lane == 0) {
            #pragma unroll
            for (int k = 0; k < 5; k++) s_red[wave][k] = vals[k];
        }
        __syncthreads();
        if (tid < 5)
            a2part[p * 5 + tid] = s_red[0][tid] + s_red[1][tid] + s_red[2][tid] + s_red[3][tid];
    }
}

__global__ void __launch_bounds__(256) final_kernel(
    const float* __restrict__ bgpart, int nbg4, int nbg5,
    const float* __restrict__ lcpart, int nA1,
    const float* __restrict__ a2part,
    int B, float* __restrict__ out)
{
    const int tid = threadIdx.x;
    float lb = 0.f, lo = 0.f, lc = 0.f, n = 0.f;
    float bg4 = 0.f, bg5 = 0.f, o4 = 0.f, c4 = 0.f, o5 = 0.f, c5 = 0.f;

    for (int i = tid; i < nA1; i += 256) lc += lcpart[i];
    for (int p = tid; p < 2 * B; p += 256) {
        float vlb = a2part[p * 5 + 0], vlo = a2part[p * 5 + 1], vn = a2part[p * 5 + 2];
        float vo  = a2part[p * 5 + 3], vc = a2part[p * 5 + 4];
        lb += vlb; lo += vlo; n += vn;
        if (p < B) { o4 += vo; c4 += vc; }
        else       { o5 += vo; c5 += vc; }
    }
    for (int i = tid; i < nbg4; i += 256) bg4 += bgpart[i];
    for (int i = tid; i < nbg5; i += 256) bg5 += bgpart[nbg4 + i];

    __shared__ float red[4][10];
    float vals[10] = { lb, lo, lc, n, bg4, bg5, o4, c4, o5, c5 };
    #pragma unroll
    for (int k = 0; k < 10; k++) {
        float v = vals[k];
        for (int off = 32; off > 0; off >>= 1) v += __shfl_down(v, off, 64);
        vals[k] = v;
    }
    if ((tid & 63) == 0) {
        #pragma unroll
        for (int k = 0; k < 10; k++) red[tid >> 6][k] = vals[k];
    }
    __syncthreads();
    if (tid == 0) {
        float t[10];
        #pragma unroll
        for (int k = 0; k < 10; k++)
            t[k] = red[0][k] + red[1][k] + red[2][k] + red[3][k];

        float lbt = t[0], lot = t[1], lct = t[2], nt = t[3];
        float bce_bg4 = t[4] - t[6];
        float bce_bg5 = t[5] - t[8];
        float cnt4 = (float)(B * 6400) - t[7];
        float cnt5 = (float)(B * 1600) - t[9];
        lot += 0.05f * ((cnt4 > 0.f) ? bce_bg4 / fmaxf(cnt4, 1.f) : 0.f);
        lot += 0.05f * ((cnt5 > 0.f) ? bce_bg5 / fmaxf(cnt5, 1.f) : 0.f);
        float nd = fmaxf(nt, 1.f);
        if (nt > 0.f) { lbt /= nd; lct /= nd; }
        lot /= fmaxf(nt, 1.f);
        out[0] = 2.0f * lbt + 1.0f * lot + 0.5f * lct;
    }
}

extern "C" void kernel_launch(void* const* d_in, const int* in_sizes, int n_in,
                              void* d_out, int out_size, void* d_ws, size_t ws_size,
                              hipStream_t stream) {
    const float* cls_p4 = (const float*)d_in[0];
    const float* reg_p4 = (const float*)d_in[1];
    const float* cls_p5 = (const float*)d_in[2];
    const float* reg_p5 = (const float*)d_in[3];
    const int*   t4_cls = (const int*)d_in[4];
    const float* t4_box = (const float*)d_in[5];
    const float* t4_mask= (const float*)d_in[6];
    const int*   t5_cls = (const int*)d_in[7];
    const float* t5_box = (const float*)d_in[8];
    const float* t5_mask= (const float*)d_in[9];

    const int B = in_sizes[0] / (C_CH * 6400);   // cls_p4: B x 81 x 80 x 80
    const int T = in_sizes[4] / B;               // t4_cls: B x T

    const int nbg4 = B * 4;                      // 4 blocks/image, 1600 cells each
    const int nbg5 = B;                          // 1 block/image, 1600 cells
    const int nbg  = nbg4 + nbg5;
    const int nA1  = 2 * B * NG;                 // focal gather blocks
    const int nA2  = 2 * B;                      // obj/bbox/dedup blocks

    float* bgpart = (float*)d_ws;
    float* lcpart = bgpart + nbg;
    float* a2part = lcpart + nA1;

    fused_kernel<<<nbg + nA1 + nA2, 256, 0, stream>>>(
        cls_p4, reg_p4, cls_p5, reg_p5,
        t4_cls, t4_box, t4_mask, t5_cls, t5_box, t5_mask,
        bgpart, lcpart, a2part, B, T, nbg4, nbg5, nA1);

    final_kernel<<<1, 256, 0, stream>>>(bgpart, nbg4, nbg5, lcpart, nA1,
                                        a2part, B, (float*)d_out);
}